// Round 6
// baseline (250.195 us; speedup 1.0000x reference)
//
#include <hip/hip_runtime.h>
#include <hip/hip_bf16.h>
#include <math.h>

#define B_ROWS 4096
#define N_ROWS 8192
#define D 128
#define NCC 16             // column chunks of 512 cols
#define K2 2.8853900818f   // 2*log2(e): exp(2c) = 2^(c*K2)

typedef __attribute__((ext_vector_type(8))) short bf16x8;
typedef __attribute__((ext_vector_type(4))) float f32x4;

#if __has_builtin(__builtin_amdgcn_exp2f)
#define EXP2(x) __builtin_amdgcn_exp2f(x)
#else
#define EXP2(x) exp2f(x)
#endif

// ---- Kernel 1: normalize pair (r, r+B); exact fp32 positive; zero cnt/out ----
__global__ __launch_bounds__(256) void normalize_pos_kernel(
    const float* __restrict__ z_i, const float* __restrict__ z_j,
    ushort* __restrict__ Z, float* __restrict__ pos_buf,
    int* __restrict__ cnt, float* __restrict__ out) {
  if (blockIdx.x == 0) {
    if (threadIdx.x < 64) cnt[threadIdx.x] = 0;
    if (threadIdx.x == 64) out[0] = 0.f;
  }
  const int wave = threadIdx.x >> 6;
  const int lane = threadIdx.x & 63;
  const int r = blockIdx.x * 4 + wave;
  float2 vi = *(const float2*)(z_i + (size_t)r * D + lane * 2);
  float2 vj = *(const float2*)(z_j + (size_t)r * D + lane * 2);
  float ssi = vi.x * vi.x + vi.y * vi.y;
  float ssj = vj.x * vj.x + vj.y * vj.y;
  float cr = vi.x * vj.x + vi.y * vj.y;
#pragma unroll
  for (int off = 32; off > 0; off >>= 1) {
    ssi += __shfl_xor(ssi, off);
    ssj += __shfl_xor(ssj, off);
    cr += __shfl_xor(cr, off);
  }
  float si = 1.0f / fmaxf(sqrtf(ssi), 1e-12f);
  float sj = 1.0f / fmaxf(sqrtf(ssj), 1e-12f);
  __hip_bfloat16 a0 = __float2bfloat16(vi.x * si);
  __hip_bfloat16 a1 = __float2bfloat16(vi.y * si);
  __hip_bfloat16 b0 = __float2bfloat16(vj.x * sj);
  __hip_bfloat16 b1 = __float2bfloat16(vj.y * sj);
  ushort2 oi, oj;
  oi.x = *(ushort*)&a0; oi.y = *(ushort*)&a1;
  oj.x = *(ushort*)&b0; oj.y = *(ushort*)&b1;
  *(ushort2*)(Z + (size_t)r * D + lane * 2) = oi;
  *(ushort2*)(Z + (size_t)(r + B_ROWS) * D + lane * 2) = oj;
  if (lane == 0) {
    float pos = 2.0f * cr * si * sj;
    pos_buf[r] = pos;
    pos_buf[r + B_ROWS] = pos;
  }
}

// ---- Kernel 2: barrier-free streaming exp-rowsum + fused finalize ----
// Grid (cc=16, rb=64) = 1024 blocks = 4/CU = 4 waves/SIMD. Block: 128 rows x
// 512 cols. Wave: 64 rows x 256 cols, A panel register-resident, B fragments
// loaded straight from L2 (Z is 2 MB, L2-resident). No LDS / barriers in loop.
__global__ __launch_bounds__(256, 4) void sim_kernel(
    const ushort* __restrict__ Z, const float* __restrict__ pos_buf,
    float* __restrict__ partials, int* __restrict__ cnt,
    float* __restrict__ out) {
  __shared__ float rowled[128];
  __shared__ float wsum[4];
  __shared__ int done_flag;

  const int cc = blockIdx.x;  // 0..15
  const int rb = blockIdx.y;  // 0..63
  const int t = threadIdx.x;
  const int lane = t & 63;
  const int w = t >> 6;
  const int wy = w >> 1, wx = w & 1;
  const int l15 = lane & 15;
  const int l4 = lane >> 4;  // 0..3

  const int r0w = rb * 128 + wy * 64;  // wave's 64-row band
  const int colw = cc * 512 + wx * 256;

  // A fragments: 64 rows x K=128, resident for the whole kernel.
  bf16x8 a[4][4];
#pragma unroll
  for (int rs = 0; rs < 4; ++rs)
#pragma unroll
    for (int ks = 0; ks < 4; ++ks)
      a[rs][ks] = *(const bf16x8*)(Z + (size_t)(r0w + rs * 16 + l15) * D + ks * 32 + l4 * 8);

  float rowacc[4][4];
#pragma unroll
  for (int rs = 0; rs < 4; ++rs)
#pragma unroll
    for (int r = 0; r < 4; ++r) rowacc[rs][r] = 0.f;

#pragma unroll 4
  for (int cs = 0; cs < 16; ++cs) {
    const int c0 = colw + cs * 16;
    bf16x8 b[4];
#pragma unroll
    for (int ks = 0; ks < 4; ++ks)
      b[ks] = *(const bf16x8*)(Z + (size_t)(c0 + l15) * D + ks * 32 + l4 * 8);

    f32x4 c4[4];
#pragma unroll
    for (int rs = 0; rs < 4; ++rs) c4[rs] = (f32x4){0.f, 0.f, 0.f, 0.f};
#pragma unroll
    for (int ks = 0; ks < 4; ++ks)
#pragma unroll
      for (int rs = 0; rs < 4; ++rs)
        c4[rs] = __builtin_amdgcn_mfma_f32_16x16x32_bf16(a[rs][ks], b[ks], c4[rs], 0, 0, 0);

    if ((unsigned)(c0 - r0w) < 64u) {
      // this 16-col window intersects the wave's 64-row band: mask gi==gj
      const int gj = c0 + l15;
#pragma unroll
      for (int rs = 0; rs < 4; ++rs) {
        const int gibase = r0w + rs * 16 + l4 * 4;
#pragma unroll
        for (int reg = 0; reg < 4; ++reg) {
          float e = EXP2(c4[rs][reg] * K2);
          rowacc[rs][reg] += (gibase + reg != gj) ? e : 0.f;
        }
      }
    } else {
#pragma unroll
      for (int rs = 0; rs < 4; ++rs)
#pragma unroll
        for (int reg = 0; reg < 4; ++reg)
          rowacc[rs][reg] += EXP2(c4[rs][reg] * K2);
    }
  }

  // reduce rowacc across the 16 column-lanes (low 4 lane bits)
#pragma unroll
  for (int rs = 0; rs < 4; ++rs)
#pragma unroll
    for (int r = 0; r < 4; ++r) {
      float v = rowacc[rs][r];
      v += __shfl_xor(v, 1);
      v += __shfl_xor(v, 2);
      v += __shfl_xor(v, 4);
      v += __shfl_xor(v, 8);
      rowacc[rs][r] = v;
    }

  // combine the wx pair via LDS (only barriers in the kernel)
  if (wx == 0 && l15 == 0) {
#pragma unroll
    for (int rs = 0; rs < 4; ++rs)
#pragma unroll
      for (int r = 0; r < 4; ++r)
        rowled[wy * 64 + rs * 16 + l4 * 4 + r] = rowacc[rs][r];
  }
  __syncthreads();
  if (wx == 1 && l15 == 0) {
#pragma unroll
    for (int rs = 0; rs < 4; ++rs)
#pragma unroll
      for (int r = 0; r < 4; ++r)
        rowled[wy * 64 + rs * 16 + l4 * 4 + r] += rowacc[rs][r];
  }
  __syncthreads();

  if (t < 128)
    partials[(size_t)cc * N_ROWS + rb * 128 + t] = rowled[t];

  // completion: last of the 16 cc-blocks for this rb finalizes its 128 rows
  __threadfence();
  if (t == 0) done_flag = (atomicAdd(&cnt[rb], 1) == NCC - 1) ? 1 : 0;
  __syncthreads();
  if (done_flag) {
    __threadfence();  // acquire: other chunks' partials now visible
    float term = 0.f;
    if (t < 128) {
      const int row = rb * 128 + t;
      float tot = 0.f;
#pragma unroll
      for (int k = 0; k < NCC; ++k) tot += partials[(size_t)k * N_ROWS + row];
      term = __logf(tot) - pos_buf[row];
    }
#pragma unroll
    for (int off = 32; off > 0; off >>= 1) term += __shfl_xor(term, off);
    if (lane == 0) wsum[w] = term;
    __syncthreads();
    if (t == 0)
      atomicAdd(out, (wsum[0] + wsum[1] + wsum[2] + wsum[3]) * (1.0f / N_ROWS));
  }
}

extern "C" void kernel_launch(void* const* d_in, const int* in_sizes, int n_in,
                              void* d_out, int out_size, void* d_ws, size_t ws_size,
                              hipStream_t stream) {
  const float* z_i = (const float*)d_in[0];
  const float* z_j = (const float*)d_in[1];
  float* out = (float*)d_out;

  ushort* Z = (ushort*)d_ws;                                        // 2 MB
  float* partials = (float*)((char*)d_ws + (size_t)N_ROWS * D * 2); // 512 KB
  float* pos_buf = partials + (size_t)NCC * N_ROWS;                 // 32 KB
  int* cnt = (int*)(pos_buf + N_ROWS);                              // 256 B

  hipLaunchKernelGGL(normalize_pos_kernel, dim3(B_ROWS / 4), dim3(256), 0,
                     stream, z_i, z_j, Z, pos_buf, cnt, out);
  hipLaunchKernelGGL(sim_kernel, dim3(NCC, N_ROWS / 128), dim3(256), 0, stream,
                     Z, pos_buf, partials, cnt, out);
}

// Round 7
// 170.601 us; speedup vs baseline: 1.4666x; 1.4666x over previous
//
#include <hip/hip_runtime.h>
#include <hip/hip_bf16.h>
#include <math.h>

#define B_ROWS 4096
#define N_ROWS 8192
#define D 128
#define NCC 16             // column chunks of 512 cols
#define K2 2.8853900818f   // 2*log2(e): exp(2c) = 2^(c*K2)

typedef __attribute__((ext_vector_type(8))) short bf16x8;
typedef __attribute__((ext_vector_type(4))) float f32x4;

#if __has_builtin(__builtin_amdgcn_exp2f)
#define EXP2(x) __builtin_amdgcn_exp2f(x)
#else
#define EXP2(x) exp2f(x)
#endif

// ---- Kernel 1: normalize pair (r, r+B); exact fp32 positive; zero cnt/out ----
__global__ __launch_bounds__(256) void normalize_pos_kernel(
    const float* __restrict__ z_i, const float* __restrict__ z_j,
    ushort* __restrict__ Z, float* __restrict__ pos_buf,
    int* __restrict__ cnt, float* __restrict__ out) {
  if (blockIdx.x == 0) {
    if (threadIdx.x < 64) cnt[threadIdx.x] = 0;
    if (threadIdx.x == 64) out[0] = 0.f;
  }
  const int wave = threadIdx.x >> 6;
  const int lane = threadIdx.x & 63;
  const int r = blockIdx.x * 4 + wave;
  float2 vi = *(const float2*)(z_i + (size_t)r * D + lane * 2);
  float2 vj = *(const float2*)(z_j + (size_t)r * D + lane * 2);
  float ssi = vi.x * vi.x + vi.y * vi.y;
  float ssj = vj.x * vj.x + vj.y * vj.y;
  float cr = vi.x * vj.x + vi.y * vj.y;
#pragma unroll
  for (int off = 32; off > 0; off >>= 1) {
    ssi += __shfl_xor(ssi, off);
    ssj += __shfl_xor(ssj, off);
    cr += __shfl_xor(cr, off);
  }
  float si = 1.0f / fmaxf(sqrtf(ssi), 1e-12f);
  float sj = 1.0f / fmaxf(sqrtf(ssj), 1e-12f);
  __hip_bfloat16 a0 = __float2bfloat16(vi.x * si);
  __hip_bfloat16 a1 = __float2bfloat16(vi.y * si);
  __hip_bfloat16 b0 = __float2bfloat16(vj.x * sj);
  __hip_bfloat16 b1 = __float2bfloat16(vj.y * sj);
  ushort2 oi, oj;
  oi.x = *(ushort*)&a0; oi.y = *(ushort*)&a1;
  oj.x = *(ushort*)&b0; oj.y = *(ushort*)&b1;
  *(ushort2*)(Z + (size_t)r * D + lane * 2) = oi;
  *(ushort2*)(Z + (size_t)(r + B_ROWS) * D + lane * 2) = oj;
  if (lane == 0) {
    float pos = 2.0f * cr * si * sj;
    pos_buf[r] = pos;
    pos_buf[r + B_ROWS] = pos;
  }
}

// ---- Kernel 2: barrier-free streaming exp-rowsum + fused finalize ----
// Grid (cc=16, rb=64) = 1024 blocks. NO min-waves launch bound: R6's (256,4)
// forced VGPR=64 -> 100+ MB scratch spills. Plain (256) compiles ~120 VGPR
// (R2 evidence) -> 4 blocks/CU from grid, no spills.
__global__ __launch_bounds__(256) void sim_kernel(
    const ushort* __restrict__ Z, const float* __restrict__ pos_buf,
    float* __restrict__ partials, int* __restrict__ cnt,
    float* __restrict__ out) {
  __shared__ float rowled[128];
  __shared__ float wsum[4];
  __shared__ int done_flag;

  const int cc = blockIdx.x;  // 0..15
  const int rb = blockIdx.y;  // 0..63
  const int t = threadIdx.x;
  const int lane = t & 63;
  const int w = t >> 6;
  const int wy = w >> 1, wx = w & 1;
  const int l15 = lane & 15;
  const int l4 = lane >> 4;  // 0..3

  const int r0w = rb * 128 + wy * 64;  // wave's 64-row band
  const int colw = cc * 512 + wx * 256;

  // A fragments: 64 rows x K=128, register-resident for the whole kernel.
  bf16x8 a[4][4];
#pragma unroll
  for (int rs = 0; rs < 4; ++rs)
#pragma unroll
    for (int ks = 0; ks < 4; ++ks)
      a[rs][ks] = *(const bf16x8*)(Z + (size_t)(r0w + rs * 16 + l15) * D + ks * 32 + l4 * 8);

  float rowacc[4][4];
#pragma unroll
  for (int rs = 0; rs < 4; ++rs)
#pragma unroll
    for (int r = 0; r < 4; ++r) rowacc[rs][r] = 0.f;

#pragma unroll 4
  for (int cs = 0; cs < 16; ++cs) {
    const int c0 = colw + cs * 16;
    bf16x8 b[4];
#pragma unroll
    for (int ks = 0; ks < 4; ++ks)
      b[ks] = *(const bf16x8*)(Z + (size_t)(c0 + l15) * D + ks * 32 + l4 * 8);

    f32x4 c4[4];
#pragma unroll
    for (int rs = 0; rs < 4; ++rs) c4[rs] = (f32x4){0.f, 0.f, 0.f, 0.f};
#pragma unroll
    for (int ks = 0; ks < 4; ++ks)
#pragma unroll
      for (int rs = 0; rs < 4; ++rs)
        c4[rs] = __builtin_amdgcn_mfma_f32_16x16x32_bf16(a[rs][ks], b[ks], c4[rs], 0, 0, 0);

    if ((unsigned)(c0 - r0w) < 64u) {
      // this 16-col window intersects the wave's 64-row band: mask gi==gj
      const int gj = c0 + l15;
#pragma unroll
      for (int rs = 0; rs < 4; ++rs) {
        const int gibase = r0w + rs * 16 + l4 * 4;
#pragma unroll
        for (int reg = 0; reg < 4; ++reg) {
          float e = EXP2(c4[rs][reg] * K2);
          rowacc[rs][reg] += (gibase + reg != gj) ? e : 0.f;
        }
      }
    } else {
#pragma unroll
      for (int rs = 0; rs < 4; ++rs)
#pragma unroll
        for (int reg = 0; reg < 4; ++reg)
          rowacc[rs][reg] += EXP2(c4[rs][reg] * K2);
    }
  }

  // reduce rowacc across the 16 column-lanes (low 4 lane bits)
#pragma unroll
  for (int rs = 0; rs < 4; ++rs)
#pragma unroll
    for (int r = 0; r < 4; ++r) {
      float v = rowacc[rs][r];
      v += __shfl_xor(v, 1);
      v += __shfl_xor(v, 2);
      v += __shfl_xor(v, 4);
      v += __shfl_xor(v, 8);
      rowacc[rs][r] = v;
    }

  // combine the wx pair via LDS (only barriers in the kernel)
  if (wx == 0 && l15 == 0) {
#pragma unroll
    for (int rs = 0; rs < 4; ++rs)
#pragma unroll
      for (int r = 0; r < 4; ++r)
        rowled[wy * 64 + rs * 16 + l4 * 4 + r] = rowacc[rs][r];
  }
  __syncthreads();
  if (wx == 1 && l15 == 0) {
#pragma unroll
    for (int rs = 0; rs < 4; ++rs)
#pragma unroll
      for (int r = 0; r < 4; ++r)
        rowled[wy * 64 + rs * 16 + l4 * 4 + r] += rowacc[rs][r];
  }
  __syncthreads();

  if (t < 128)
    partials[(size_t)cc * N_ROWS + rb * 128 + t] = rowled[t];

  // completion: last of the 16 cc-blocks for this rb finalizes its 128 rows
  __threadfence();
  if (t == 0) done_flag = (atomicAdd(&cnt[rb], 1) == NCC - 1) ? 1 : 0;
  __syncthreads();
  if (done_flag) {
    __threadfence();  // acquire: other chunks' partials now visible
    float term = 0.f;
    if (t < 128) {
      const int row = rb * 128 + t;
      float tot = 0.f;
#pragma unroll
      for (int k = 0; k < NCC; ++k) tot += partials[(size_t)k * N_ROWS + row];
      term = __logf(tot) - pos_buf[row];
    }
#pragma unroll
    for (int off = 32; off > 0; off >>= 1) term += __shfl_xor(term, off);
    if (lane == 0) wsum[w] = term;
    __syncthreads();
    if (t == 0)
      atomicAdd(out, (wsum[0] + wsum[1] + wsum[2] + wsum[3]) * (1.0f / N_ROWS));
  }
}

extern "C" void kernel_launch(void* const* d_in, const int* in_sizes, int n_in,
                              void* d_out, int out_size, void* d_ws, size_t ws_size,
                              hipStream_t stream) {
  const float* z_i = (const float*)d_in[0];
  const float* z_j = (const float*)d_in[1];
  float* out = (float*)d_out;

  ushort* Z = (ushort*)d_ws;                                        // 2 MB
  float* partials = (float*)((char*)d_ws + (size_t)N_ROWS * D * 2); // 512 KB
  float* pos_buf = partials + (size_t)NCC * N_ROWS;                 // 32 KB
  int* cnt = (int*)(pos_buf + N_ROWS);                              // 256 B

  hipLaunchKernelGGL(normalize_pos_kernel, dim3(B_ROWS / 4), dim3(256), 0,
                     stream, z_i, z_j, Z, pos_buf, cnt, out);
  hipLaunchKernelGGL(sim_kernel, dim3(NCC, N_ROWS / 128), dim3(256), 0, stream,
                     Z, pos_buf, partials, cnt, out);
}